// Round 14
// baseline (94.916 us; speedup 1.0000x reference)
//
#include <hip/hip_runtime.h>
#include <hip/hip_bf16.h>

typedef unsigned short u16;
using frag_ab = __attribute__((ext_vector_type(8))) short;
using f32x4   = __attribute__((ext_vector_type(4))) float;
using u16x4   = __attribute__((ext_vector_type(4))) unsigned short;
using u16x8   = __attribute__((ext_vector_type(8))) unsigned short;

#define N_CTX   2048
#define NBATCH  2
#define CDIM    1024
#define NH      16
#define HD      64

__device__ __forceinline__ u16 f2b(float f) {
  __hip_bfloat16 h = __float2bfloat16(f);
  return __builtin_bit_cast(u16, h);
}

__device__ __forceinline__ f32x4 mfma16(frag_ab a, frag_ab b, f32x4 c) {
  return __builtin_amdgcn_mfma_f32_16x16x32_bf16(a, b, c, 0, 0, 0);
}

#define GLDS16(src, dst) \
  __builtin_amdgcn_global_load_lds((const __attribute__((address_space(1))) void*)(src), \
                                   (__attribute__((address_space(3))) void*)(dst), 16, 0, 0)

// ---------------- merged prep kernel ----------------
__global__ __launch_bounds__(256) void prep_all(const float* __restrict__ x, u16* __restrict__ xb,
                                                const float* __restrict__ Wa, u16* __restrict__ Wab,
                                                const float* __restrict__ Wp, u16* __restrict__ Wpb) {
  __shared__ float tile[32][33];
  const int blk = blockIdx.x;
  if (blk < 2048) {
    int i = blk * 256 + threadIdx.x;
    const f32x4* ip = (const f32x4*)x;
    f32x4 a = ip[2 * i], b2 = ip[2 * i + 1];
    u16x8 r;
    #pragma unroll
    for (int j = 0; j < 4; ++j) { r[j] = f2b(a[j]); r[4 + j] = f2b(b2[j]); }
    ((u16x8*)xb)[i] = r;
    return;
  }
  const float* in; u16* out; int K, N, bx, by;
  if (blk < 5120) {
    int idx = blk - 2048; in = Wa; out = Wab; K = CDIM; N = 3 * CDIM;
    bx = idx % 96; by = idx / 96;
  } else {
    int idx = blk - 5120; in = Wp; out = Wpb; K = CDIM; N = CDIM;
    bx = idx & 31; by = idx >> 5;
  }
  int n0 = bx * 32, k0 = by * 32;
  int c = threadIdx.x & 31, r0 = threadIdx.x >> 5;
  #pragma unroll
  for (int i = 0; i < 4; ++i) {
    int r = r0 + i * 8;
    tile[r][c] = in[(size_t)(k0 + r) * N + n0 + c];
  }
  __syncthreads();
  int n = threadIdx.x >> 3, kq = threadIdx.x & 7;
  u16x4 pk;
  #pragma unroll
  for (int j = 0; j < 4; ++j) pk[j] = f2b(tile[kq * 4 + j][n]);
  *(u16x4*)&out[(size_t)(n0 + n) * K + k0 + kq * 4] = pk;
}

// ---------------- GEMM1: 128x192 tile, 8 waves, 2 blocks/CU ----------------
__global__ __launch_bounds__(512, 4) void gemm_qkv128(const u16* __restrict__ A,
                                                      const u16* __restrict__ Bt,
                                                      const float* __restrict__ bias,
                                                      u16* __restrict__ Qo, u16* __restrict__ Ko,
                                                      u16* __restrict__ Vto) {
  __shared__ __align__(16) u16 As[2][128 * 64];   // 32 KB
  __shared__ __align__(16) u16 Bs[2][192 * 64];   // 48 KB
  const int tid = threadIdx.x, w = tid >> 6, lane = tid & 63;
  const int g = lane >> 4, lr = lane & 15;
  const int wr = w >> 2, wc = w & 3;
  const int bid = blockIdx.x;
  const int swz = (bid & 7) * 64 + (bid >> 3);
  const int tm = (swz & 31) * 128, tn = (swz >> 5) * 192;

  f32x4 acc[4][3];
  #pragma unroll
  for (int mi = 0; mi < 4; ++mi)
    #pragma unroll
    for (int ni = 0; ni < 3; ++ni)
      acc[mi][ni] = (f32x4){0.f, 0.f, 0.f, 0.f};

  auto STAGE = [&](int d, int kt) {
    const int k0 = kt << 6;
    #pragma unroll
    for (int j = 0; j < 2; ++j) {
      int ci = j * 512 + tid, row = ci >> 3, c8 = ci & 7;
      GLDS16(A + (size_t)(tm + row) * CDIM + k0 + ((c8 ^ (row & 7)) << 3),
             &As[d][row * 64 + c8 * 8]);
    }
    #pragma unroll
    for (int j = 0; j < 3; ++j) {
      int ci = j * 512 + tid, row = ci >> 3, c8 = ci & 7;
      GLDS16(Bt + (size_t)(tn + row) * CDIM + k0 + ((c8 ^ (row & 7)) << 3),
             &Bs[d][row * 64 + c8 * 8]);
    }
  };

  STAGE(0, 0);
  asm volatile("s_waitcnt vmcnt(0)" ::: "memory");
  __builtin_amdgcn_s_barrier();

  const int x7 = lr & 7;
  for (int t = 0; t < 16; ++t) {
    const int cur = t & 1;
    if (t < 15) STAGE(cur ^ 1, t + 1);

    frag_ab af[4][2], bf[3][2];
    #pragma unroll
    for (int mi = 0; mi < 4; ++mi) {
      int row = wr * 64 + mi * 16 + lr;
      #pragma unroll
      for (int ks = 0; ks < 2; ++ks)
        af[mi][ks] = *(const frag_ab*)&As[cur][row * 64 + ((((ks << 2) | g) ^ x7) << 3)];
    }
    #pragma unroll
    for (int ni = 0; ni < 3; ++ni) {
      int row = wc * 48 + ni * 16 + lr;
      #pragma unroll
      for (int ks = 0; ks < 2; ++ks)
        bf[ni][ks] = *(const frag_ab*)&Bs[cur][row * 64 + ((((ks << 2) | g) ^ x7) << 3)];
    }
    __builtin_amdgcn_s_setprio(1);
    #pragma unroll
    for (int mi = 0; mi < 4; ++mi)
      #pragma unroll
      for (int ni = 0; ni < 3; ++ni)
        #pragma unroll
        for (int ks = 0; ks < 2; ++ks)
          acc[mi][ni] = mfma16(af[mi][ks], bf[ni][ks], acc[mi][ni]);
    __builtin_amdgcn_s_setprio(0);

    asm volatile("s_waitcnt vmcnt(0)" ::: "memory");
    __builtin_amdgcn_s_barrier();
  }

  #pragma unroll
  for (int ni = 0; ni < 3; ++ni) {
    int n = tn + wc * 48 + ni * 16 + lr;
    float bv = bias[n];
    int which = n >> 10, c = n & 1023, h = c >> 6, d = c & 63;
    #pragma unroll
    for (int mi = 0; mi < 4; ++mi) {
      if (which == 2) {
        int t0 = tm + wr * 64 + mi * 16 + g * 4;
        int bb = t0 >> 11, tt = t0 & (N_CTX - 1);
        u16x4 pk;
        #pragma unroll
        for (int r = 0; r < 4; ++r) pk[r] = f2b(acc[mi][ni][r] + bv);
        *(u16x4*)&Vto[((size_t)(bb * NH + h) * HD + d) * N_CTX + tt] = pk;
      } else {
        u16* dst = (which == 0) ? Qo : Ko;
        float scl = (which == 0) ? 0.180336881f : 1.0f;   // (1/8)*log2(e)
        #pragma unroll
        for (int r = 0; r < 4; ++r) {
          int m = tm + wr * 64 + mi * 16 + g * 4 + r;
          int bb = m >> 11, tt = m & (N_CTX - 1);
          dst[((size_t)(bb * NH + h) * N_CTX + tt) * HD + d] = f2b((acc[mi][ni][r] + bv) * scl);
        }
      }
    }
  }
}

// ---------------- GEMM2: 128x64 tile, 3-buffer counted-vmcnt pipeline (fp32 out) ---------
__global__ __launch_bounds__(512, 4) void gemm_proj128(const u16* __restrict__ A,
                                                       const u16* __restrict__ Bt,
                                                       const float* __restrict__ bias,
                                                       float* __restrict__ out) {
  __shared__ __align__(16) u16 As[3][128 * 64];   // 48 KB
  __shared__ __align__(16) u16 Bs[3][64 * 64];    // 24 KB
  const int tid = threadIdx.x, w = tid >> 6, lane = tid & 63;
  const int g = lane >> 4, lr = lane & 15;
  const int wr = w >> 1, wc = w & 1;
  const int bid = blockIdx.x;
  const int swz = (bid & 7) * 64 + (bid >> 3);
  const int tm = (swz & 31) * 128, tn = (swz >> 5) * 64;

  f32x4 acc[2][2];
  #pragma unroll
  for (int mi = 0; mi < 2; ++mi)
    #pragma unroll
    for (int ni = 0; ni < 2; ++ni)
      acc[mi][ni] = (f32x4){0.f, 0.f, 0.f, 0.f};

  auto STAGE = [&](int d, int kt) {
    const int k0 = kt << 6;
    #pragma unroll
    for (int j = 0; j < 2; ++j) {
      int ci = j * 512 + tid, row = ci >> 3, c8 = ci & 7;
      GLDS16(A + (size_t)(tm + row) * CDIM + k0 + ((c8 ^ (row & 7)) << 3),
             &As[d][row * 64 + c8 * 8]);
    }
    {
      int row = tid >> 3, c8 = tid & 7;
      GLDS16(Bt + (size_t)(tn + row) * CDIM + k0 + ((c8 ^ (row & 7)) << 3),
             &Bs[d][row * 64 + c8 * 8]);
    }
  };

  STAGE(0, 0);
  STAGE(1, 1);
  asm volatile("s_waitcnt vmcnt(3)" ::: "memory");
  __builtin_amdgcn_s_barrier();

  const int x7 = lr & 7;
  int cur = 0;
  for (int t = 0; t < 16; ++t) {
    if (t < 14) STAGE((cur + 2) % 3, t + 2);

    frag_ab af[2][2], bf[2][2];
    #pragma unroll
    for (int mi = 0; mi < 2; ++mi) {
      int row = wr * 32 + mi * 16 + lr;
      #pragma unroll
      for (int ks = 0; ks < 2; ++ks)
        af[mi][ks] = *(const frag_ab*)&As[cur][row * 64 + ((((ks << 2) | g) ^ x7) << 3)];
    }
    #pragma unroll
    for (int ni = 0; ni < 2; ++ni) {
      int row = wc * 32 + ni * 16 + lr;
      #pragma unroll
      for (int ks = 0; ks < 2; ++ks)
        bf[ni][ks] = *(const frag_ab*)&Bs[cur][row * 64 + ((((ks << 2) | g) ^ x7) << 3)];
    }
    __builtin_amdgcn_s_setprio(1);
    #pragma unroll
    for (int mi = 0; mi < 2; ++mi)
      #pragma unroll
      for (int ni = 0; ni < 2; ++ni)
        #pragma unroll
        for (int ks = 0; ks < 2; ++ks)
          acc[mi][ni] = mfma16(af[mi][ks], bf[ni][ks], acc[mi][ni]);
    __builtin_amdgcn_s_setprio(0);

    if (t < 14) { asm volatile("s_waitcnt vmcnt(3)" ::: "memory"); }
    else        { asm volatile("s_waitcnt vmcnt(0)" ::: "memory"); }
    __builtin_amdgcn_s_barrier();
    cur = (cur + 1) % 3;
  }

  #pragma unroll
  for (int ni = 0; ni < 2; ++ni) {
    int n = tn + wc * 32 + ni * 16 + lr;
    float bv = bias[n];
    #pragma unroll
    for (int mi = 0; mi < 2; ++mi)
      #pragma unroll
      for (int r = 0; r < 4; ++r) {
        int m = tm + wr * 32 + mi * 16 + g * 4 + r;
        out[(size_t)m * CDIM + n] = acc[mi][ni][r] + bv;
      }
  }
}

// ---------------- flash attention (causal): QBLK=128 paired, 4 q-groups/wave -------------
// Block (bh, p in [0,8)) owns rows [128p,128p+128) (A) and [2048-128(p+1), 2048-128p) (B):
// uniform 34 tile-units/block. 8 waves = 2 k-parities x 4 row-waves; each wave owns 16 rows
// in each region x 2 groups -> one kf/vf LDS read feeds up to 4 q-groups (4x less LDS-read
// per MFMA than R12). No-max exp2 softmax => split-K exact; cross-parity combine via the
// KV buffer reused as f32 scratch. 1 block/CU; per-iter vmcnt(0) covered by ~4x compute.
__global__ __launch_bounds__(512, 2) void attn_fwd(const u16* __restrict__ Q, const u16* __restrict__ K,
                                                   const u16* __restrict__ Vt, u16* __restrict__ Y) {
  __shared__ __align__(16) u16 KV[8][64 * 64];   // 64 KB: K tiles [0..3], V tiles [4..7]
  __shared__ float PSb[256];                     // parity-1 partial row sums
  const int orig = blockIdx.x;                   // 256 blocks = 8 XCD x (4 bh x 8 p)
  const int bh = (orig & 7) * 4 + ((orig >> 3) & 3);
  const int p  = orig >> 5;                      // 0..7
  const int RA = 128 * p, RB = 2048 - 128 * (p + 1);
  const int tid = threadIdx.x, w8 = tid >> 6, lane = tid & 63;
  const int grp = w8 >> 2, w = w8 & 3;           // grp = k-parity, w = row-wave
  const int g = lane >> 4, lr = lane & 15;
  const size_t base = (size_t)bh * N_CTX * HD;
  const u16* Kbh = K + base;
  const u16* Vbh = Vt + base;

  const int c8 = tid & 7, srow = (tid >> 3) & 63;
  const size_t kOff = (size_t)srow * HD + (size_t)((c8 ^ (srow & 7)) * 8);
  const size_t vOff = (size_t)srow * N_CTX + (size_t)((c8 ^ (srow & 7)) * 8);

  // q fragments: 4 groups (A0, A1, B0, B1), 16 rows each
  frag_ab qA0[2], qA1[2], qB0[2], qB1[2];
  {
    const u16* q0 = Q + base + (size_t)(RA + w * 32 + lr) * HD + g * 8;
    qA0[0] = *(const frag_ab*)q0;  qA0[1] = *(const frag_ab*)(q0 + 32);
    const u16* q1 = Q + base + (size_t)(RA + w * 32 + 16 + lr) * HD + g * 8;
    qA1[0] = *(const frag_ab*)q1;  qA1[1] = *(const frag_ab*)(q1 + 32);
    const u16* q2 = Q + base + (size_t)(RB + w * 32 + lr) * HD + g * 8;
    qB0[0] = *(const frag_ab*)q2;  qB0[1] = *(const frag_ab*)(q2 + 32);
    const u16* q3 = Q + base + (size_t)(RB + w * 32 + 16 + lr) * HD + g * 8;
    qB1[0] = *(const frag_ab*)q3;  qB1[1] = *(const frag_ab*)(q3 + 32);
  }
  const int off0 = (w * 32) & 63, off1 = (w * 32 + 16) & 63;
  const int TA0 = (RA + w * 32) >> 6, TA1 = (RA + w * 32 + 16) >> 6;
  const int TB0 = (RB + w * 32) >> 6, TB1 = (RB + w * 32 + 16) >> 6;

  f32x4 oA0[4], oA1[4], oB0[4], oB1[4];
  float pA0 = 0.f, pA1 = 0.f, pB0 = 0.f, pB1 = 0.f;
  #pragma unroll
  for (int d = 0; d < 4; ++d) {
    oA0[d] = (f32x4){0,0,0,0};  oA1[d] = (f32x4){0,0,0,0};
    oB0[d] = (f32x4){0,0,0,0};  oB1[d] = (f32x4){0,0,0,0};
  }

  auto STAGE = [&](int b, int kt) {
    GLDS16(Kbh + (size_t)kt * 64 * HD + kOff, &KV[b][(size_t)tid * 8]);
    GLDS16(Vbh + (size_t)kt * 64 + vOff,      &KV[4 + b][(size_t)tid * 8]);
  };

  // QK^T + mask + exp2 + partial-sum + pack for one 16-row group
  frag_ab kf[4][2];
  auto qk = [&](const frag_ab (&qf)[2], frag_ab (&pa)[2], float& ps, bool diag, int off) {
    f32x4 s[4];
    __builtin_amdgcn_s_setprio(1);
    #pragma unroll
    for (int j = 0; j < 4; ++j) {
      f32x4 a = (f32x4){0.f, 0.f, 0.f, 0.f};
      a = mfma16(kf[j][0], qf[0], a);
      a = mfma16(kf[j][1], qf[1], a);
      s[j] = a;
    }
    __builtin_amdgcn_s_setprio(0);
    if (diag) {
      #pragma unroll
      for (int nf = 0; nf < 4; ++nf)
        #pragma unroll
        for (int r = 0; r < 4; ++r)
          if (nf * 16 + g * 4 + r > off + lr) s[nf][r] = -1e30f;
    }
    #pragma unroll
    for (int j = 0; j < 4; ++j)
      #pragma unroll
      for (int r = 0; r < 4; ++r)
        s[j][r] = __builtin_amdgcn_exp2f(s[j][r]);
    ps += ((s[0][0]+s[0][1])+(s[0][2]+s[0][3])) + ((s[1][0]+s[1][1])+(s[1][2]+s[1][3]))
        + ((s[2][0]+s[2][1])+(s[2][2]+s[2][3])) + ((s[3][0]+s[3][1])+(s[3][2]+s[3][3]));
    #pragma unroll
    for (int ks = 0; ks < 2; ++ks)
      #pragma unroll
      for (int j = 0; j < 4; ++j) {
        pa[ks][j]     = (short)f2b(s[2 * ks][j]);
        pa[ks][4 + j] = (short)f2b(s[2 * ks + 1][j]);
      }
  };

  const int niter = 16 - p;
  STAGE(0, 0);
  STAGE(1, 1);
  asm volatile("s_waitcnt vmcnt(0)" ::: "memory");
  __builtin_amdgcn_s_barrier();

  for (int i = 0; i < niter; ++i) {
    const int t = 2 * i + grp;
    if (i + 1 < niter) { STAGE((2 * i + 2) & 3, 2 * i + 2); STAGE((2 * i + 3) & 3, 2 * i + 3); }

    const bool aB0 = t <= TB0, aB1 = t <= TB1;
    const bool aA0 = t <= TA0, aA1 = t <= TA1;
    if (aB0 | aB1) {                              // A-region limits are always < B limits
      const int bb = t & 3;
      #pragma unroll
      for (int nf = 0; nf < 4; ++nf)
        #pragma unroll
        for (int ks = 0; ks < 2; ++ks)
          kf[nf][ks] = *(const frag_ab*)&KV[bb][(size_t)(nf * 16 + lr) * 64 +
                                                (size_t)((((ks << 2) | g) ^ (lr & 7)) * 8)];
      frag_ab paA0[2], paA1[2], paB0[2], paB1[2];
      if (aB0) qk(qB0, paB0, pB0, t == TB0, off0);
      if (aB1) qk(qB1, paB1, pB1, t == TB1, off1);
      if (aA0) qk(qA0, paA0, pA0, t == TA0, off0);
      if (aA1) qk(qA1, paA1, pA1, t == TA1, off1);

      #pragma unroll
      for (int d = 0; d < 4; ++d) {
        const int row = (d * 16 + lr) * 64;
        frag_ab vf[2];
        #pragma unroll
        for (int ks = 0; ks < 2; ++ks) {
          u16x4 lo = *(const u16x4*)&KV[4 + bb][row + (((ks * 4 + (g >> 1)) ^ (lr & 7)) * 8) + (g & 1) * 4];
          u16x4 hi = *(const u16x4*)&KV[4 + bb][row + (((ks * 4 + 2 + (g >> 1)) ^ (lr & 7)) * 8) + (g & 1) * 4];
          #pragma unroll
          for (int j = 0; j < 4; ++j) { vf[ks][j] = (short)lo[j]; vf[ks][4 + j] = (short)hi[j]; }
        }
        __builtin_amdgcn_s_setprio(1);
        if (aB0) { oB0[d] = mfma16(paB0[0], vf[0], oB0[d]); oB0[d] = mfma16(paB0[1], vf[1], oB0[d]); }
        if (aB1) { oB1[d] = mfma16(paB1[0], vf[0], oB1[d]); oB1[d] = mfma16(paB1[1], vf[1], oB1[d]); }
        if (aA0) { oA0[d] = mfma16(paA0[0], vf[0], oA0[d]); oA0[d] = mfma16(paA0[1], vf[1], oA0[d]); }
        if (aA1) { oA1[d] = mfma16(paA1[0], vf[0], oA1[d]); oA1[d] = mfma16(paA1[1], vf[1], oA1[d]); }
        __builtin_amdgcn_s_setprio(0);
      }
    }

    asm volatile("s_waitcnt vmcnt(0)" ::: "memory");
    __builtin_amdgcn_s_barrier();
  }

  // ---- epilogue: cross-parity combine via LDS (KV reused as f32 scratch), then Y ----
  pA0 += __shfl_xor(pA0, 16, 64);  pA0 += __shfl_xor(pA0, 32, 64);
  pA1 += __shfl_xor(pA1, 16, 64);  pA1 += __shfl_xor(pA1, 32, 64);
  pB0 += __shfl_xor(pB0, 16, 64);  pB0 += __shfl_xor(pB0, 32, 64);
  pB1 += __shfl_xor(pB1, 16, 64);  pB1 += __shfl_xor(pB1, 32, 64);

  float* SO = (float*)&KV[0][0];   // 256 rows x 64 cols f32 = 64 KB (A rows 0..127, B rows 128..255)

  if (grp == 1) {
    #pragma unroll
    for (int d = 0; d < 4; ++d)
      #pragma unroll
      for (int r = 0; r < 4; ++r) {
        SO[(w * 32 + g * 4 + r) * 64 + d * 16 + lr]            = oA0[d][r];
        SO[(w * 32 + 16 + g * 4 + r) * 64 + d * 16 + lr]       = oA1[d][r];
        SO[(128 + w * 32 + g * 4 + r) * 64 + d * 16 + lr]      = oB0[d][r];
        SO[(128 + w * 32 + 16 + g * 4 + r) * 64 + d * 16 + lr] = oB1[d][r];
      }
    if (g == 0) {
      PSb[w * 32 + lr]            = pA0;
      PSb[w * 32 + 16 + lr]       = pA1;
      PSb[128 + w * 32 + lr]      = pB0;
      PSb[128 + w * 32 + 16 + lr] = pB1;
    }
  }
  __syncthreads();

  if (grp == 0) {
    const int b = bh >> 4, h = bh & 15;
    float liA0 = 1.0f / (pA0 + PSb[w * 32 + lr]);
    float liA1 = 1.0f / (pA1 + PSb[w * 32 + 16 + lr]);
    float liB0 = 1.0f / (pB0 + PSb[128 + w * 32 + lr]);
    float liB1 = 1.0f / (pB1 + PSb[128 + w * 32 + 16 + lr]);
    #pragma unroll
    for (int r = 0; r < 4; ++r) {
      int src = (lane & 48) | (((lane >> 4) & 3) * 4 + r);
      float lA0 = __shfl(liA0, src, 64), lA1 = __shfl(liA1, src, 64);
      float lB0 = __shfl(liB0, src, 64), lB1 = __shfl(liB1, src, 64);
      int rA0 = RA + w * 32 + g * 4 + r,      rA1 = RA + w * 32 + 16 + g * 4 + r;
      int rB0 = RB + w * 32 + g * 4 + r,      rB1 = RB + w * 32 + 16 + g * 4 + r;
      #pragma unroll
      for (int d = 0; d < 4; ++d) {
        int col = h * HD + d * 16 + lr;
        float vA0 = (oA0[d][r] + SO[(w * 32 + g * 4 + r) * 64 + d * 16 + lr]) * lA0;
        float vA1 = (oA1[d][r] + SO[(w * 32 + 16 + g * 4 + r) * 64 + d * 16 + lr]) * lA1;
        float vB0 = (oB0[d][r] + SO[(128 + w * 32 + g * 4 + r) * 64 + d * 16 + lr]) * lB0;
        float vB1 = (oB1[d][r] + SO[(128 + w * 32 + 16 + g * 4 + r) * 64 + d * 16 + lr]) * lB1;
        Y[((size_t)(b * N_CTX + rA0)) * CDIM + col] = f2b(vA0);
        Y[((size_t)(b * N_CTX + rA1)) * CDIM + col] = f2b(vA1);
        Y[((size_t)(b * N_CTX + rB0)) * CDIM + col] = f2b(vB0);
        Y[((size_t)(b * N_CTX + rB1)) * CDIM + col] = f2b(vB1);
      }
    }
  }
}

// ---------------- launch ----------------
extern "C" void kernel_launch(void* const* d_in, const int* in_sizes, int n_in,
                              void* d_out, int out_size, void* d_ws, size_t ws_size,
                              hipStream_t stream) {
  const float* x      = (const float*)d_in[0];
  const float* W_attn = (const float*)d_in[1];
  const float* b_attn = (const float*)d_in[2];
  const float* W_proj = (const float*)d_in[3];
  const float* b_proj = (const float*)d_in[4];
  float* out = (float*)d_out;
  char* ws = (char*)d_ws;

  u16* xb  = (u16*)(ws);                       // 8 MB  (reused for y)
  u16* Wab = (u16*)(ws + ((size_t)8 << 20));   // 6 MB  W_attn^T bf16
  u16* Wpb = (u16*)(ws + ((size_t)14 << 20));  // 2 MB  W_proj^T bf16
  u16* Qb  = (u16*)(ws + ((size_t)16 << 20));  // 8 MB  (pre-scaled)
  u16* Kb  = (u16*)(ws + ((size_t)24 << 20));  // 8 MB
  u16* Vtb = (u16*)(ws + ((size_t)32 << 20));  // 8 MB  V^T
  u16* yb  = xb;

  prep_all<<<6144, 256, 0, stream>>>(x, xb, W_attn, Wab, W_proj, Wpb);
  gemm_qkv128<<<512, 512, 0, stream>>>(xb, Wab, b_attn, Qb, Kb, Vtb);
  attn_fwd<<<256, 512, 0, stream>>>(Qb, Kb, Vtb, yb);
  gemm_proj128<<<512, 512, 0, stream>>>(yb, Wpb, b_proj, out);
}

// Round 15
// 90.391 us; speedup vs baseline: 1.0501x; 1.0501x over previous
//
#include <hip/hip_runtime.h>
#include <hip/hip_bf16.h>

typedef unsigned short u16;
using frag_ab = __attribute__((ext_vector_type(8))) short;
using f32x4   = __attribute__((ext_vector_type(4))) float;
using u16x4   = __attribute__((ext_vector_type(4))) unsigned short;
using u16x8   = __attribute__((ext_vector_type(8))) unsigned short;

#define N_CTX   2048
#define NBATCH  2
#define CDIM    1024
#define NH      16
#define HD      64

__device__ __forceinline__ u16 f2b(float f) {
  __hip_bfloat16 h = __float2bfloat16(f);
  return __builtin_bit_cast(u16, h);
}

__device__ __forceinline__ f32x4 mfma16(frag_ab a, frag_ab b, f32x4 c) {
  return __builtin_amdgcn_mfma_f32_16x16x32_bf16(a, b, c, 0, 0, 0);
}

#define GLDS16(src, dst) \
  __builtin_amdgcn_global_load_lds((const __attribute__((address_space(1))) void*)(src), \
                                   (__attribute__((address_space(3))) void*)(dst), 16, 0, 0)

// ---------------- merged prep kernel ----------------
__global__ __launch_bounds__(256) void prep_all(const float* __restrict__ x, u16* __restrict__ xb,
                                                const float* __restrict__ Wa, u16* __restrict__ Wab,
                                                const float* __restrict__ Wp, u16* __restrict__ Wpb) {
  __shared__ float tile[32][33];
  const int blk = blockIdx.x;
  if (blk < 2048) {
    int i = blk * 256 + threadIdx.x;
    const f32x4* ip = (const f32x4*)x;
    f32x4 a = ip[2 * i], b2 = ip[2 * i + 1];
    u16x8 r;
    #pragma unroll
    for (int j = 0; j < 4; ++j) { r[j] = f2b(a[j]); r[4 + j] = f2b(b2[j]); }
    ((u16x8*)xb)[i] = r;
    return;
  }
  const float* in; u16* out; int K, N, bx, by;
  if (blk < 5120) {
    int idx = blk - 2048; in = Wa; out = Wab; K = CDIM; N = 3 * CDIM;
    bx = idx % 96; by = idx / 96;
  } else {
    int idx = blk - 5120; in = Wp; out = Wpb; K = CDIM; N = CDIM;
    bx = idx & 31; by = idx >> 5;
  }
  int n0 = bx * 32, k0 = by * 32;
  int c = threadIdx.x & 31, r0 = threadIdx.x >> 5;
  #pragma unroll
  for (int i = 0; i < 4; ++i) {
    int r = r0 + i * 8;
    tile[r][c] = in[(size_t)(k0 + r) * N + n0 + c];
  }
  __syncthreads();
  int n = threadIdx.x >> 3, kq = threadIdx.x & 7;
  u16x4 pk;
  #pragma unroll
  for (int j = 0; j < 4; ++j) pk[j] = f2b(tile[kq * 4 + j][n]);
  *(u16x4*)&out[(size_t)(n0 + n) * K + k0 + kq * 4] = pk;
}

// ---------------- GEMM1: 128x192 tile, 4 waves (2x2) of 64x96, 2 blocks/CU ---------------
// LDS-read-bound fix: per-wave area 64x96 (acc[4][6]) cuts ds_read_b128 per MFMA by 1.4x
// vs the 8-wave 64x48 layout (reads ~ perimeter, MFMA ~ area). LDS 80 KB -> 2 blocks/CU.
__global__ __launch_bounds__(256, 2) void gemm_qkv128(const u16* __restrict__ A,
                                                      const u16* __restrict__ Bt,
                                                      const float* __restrict__ bias,
                                                      u16* __restrict__ Qo, u16* __restrict__ Ko,
                                                      u16* __restrict__ Vto) {
  __shared__ __align__(16) u16 As[2][128 * 64];   // 32 KB
  __shared__ __align__(16) u16 Bs[2][192 * 64];   // 48 KB
  const int tid = threadIdx.x, w = tid >> 6, lane = tid & 63;
  const int g = lane >> 4, lr = lane & 15;
  const int wr = w >> 1, wc = w & 1;              // 2x2 waves; per-wave 64x96
  const int bid = blockIdx.x;
  const int swz = (bid & 7) * 64 + (bid >> 3);
  const int tm = (swz & 31) * 128, tn = (swz >> 5) * 192;

  f32x4 acc[4][6];
  #pragma unroll
  for (int mi = 0; mi < 4; ++mi)
    #pragma unroll
    for (int ni = 0; ni < 6; ++ni)
      acc[mi][ni] = (f32x4){0.f, 0.f, 0.f, 0.f};

  auto STAGE = [&](int d, int kt) {
    const int k0 = kt << 6;
    #pragma unroll
    for (int j = 0; j < 4; ++j) {                 // A: 1024 chunks / 256 threads
      int ci = j * 256 + tid, row = ci >> 3, c8 = ci & 7;
      GLDS16(A + (size_t)(tm + row) * CDIM + k0 + ((c8 ^ (row & 7)) << 3),
             &As[d][row * 64 + c8 * 8]);
    }
    #pragma unroll
    for (int j = 0; j < 6; ++j) {                 // B: 1536 chunks
      int ci = j * 256 + tid, row = ci >> 3, c8 = ci & 7;
      GLDS16(Bt + (size_t)(tn + row) * CDIM + k0 + ((c8 ^ (row & 7)) << 3),
             &Bs[d][row * 64 + c8 * 8]);
    }
  };

  STAGE(0, 0);
  asm volatile("s_waitcnt vmcnt(0)" ::: "memory");
  __builtin_amdgcn_s_barrier();

  const int x7 = lr & 7;
  for (int t = 0; t < 16; ++t) {
    const int cur = t & 1;
    if (t < 15) STAGE(cur ^ 1, t + 1);

    frag_ab af[4][2], bf[6][2];
    #pragma unroll
    for (int mi = 0; mi < 4; ++mi) {
      int row = wr * 64 + mi * 16 + lr;
      #pragma unroll
      for (int ks = 0; ks < 2; ++ks)
        af[mi][ks] = *(const frag_ab*)&As[cur][row * 64 + ((((ks << 2) | g) ^ x7) << 3)];
    }
    #pragma unroll
    for (int ni = 0; ni < 6; ++ni) {
      int row = wc * 96 + ni * 16 + lr;
      #pragma unroll
      for (int ks = 0; ks < 2; ++ks)
        bf[ni][ks] = *(const frag_ab*)&Bs[cur][row * 64 + ((((ks << 2) | g) ^ x7) << 3)];
    }
    __builtin_amdgcn_s_setprio(1);
    #pragma unroll
    for (int mi = 0; mi < 4; ++mi)
      #pragma unroll
      for (int ni = 0; ni < 6; ++ni)
        #pragma unroll
        for (int ks = 0; ks < 2; ++ks)
          acc[mi][ni] = mfma16(af[mi][ks], bf[ni][ks], acc[mi][ni]);
    __builtin_amdgcn_s_setprio(0);

    asm volatile("s_waitcnt vmcnt(0)" ::: "memory");
    __builtin_amdgcn_s_barrier();
  }

  #pragma unroll
  for (int ni = 0; ni < 6; ++ni) {
    int n = tn + wc * 96 + ni * 16 + lr;          // 0..3071
    float bv = bias[n];
    int which = n >> 10, c = n & 1023, h = c >> 6, d = c & 63;
    #pragma unroll
    for (int mi = 0; mi < 4; ++mi) {
      if (which == 2) {
        int t0 = tm + wr * 64 + mi * 16 + g * 4;
        int bb = t0 >> 11, tt = t0 & (N_CTX - 1);
        u16x4 pk;
        #pragma unroll
        for (int r = 0; r < 4; ++r) pk[r] = f2b(acc[mi][ni][r] + bv);
        *(u16x4*)&Vto[((size_t)(bb * NH + h) * HD + d) * N_CTX + tt] = pk;
      } else {
        u16* dst = (which == 0) ? Qo : Ko;
        float scl = (which == 0) ? 0.180336881f : 1.0f;   // (1/8)*log2(e)
        #pragma unroll
        for (int r = 0; r < 4; ++r) {
          int m = tm + wr * 64 + mi * 16 + g * 4 + r;
          int bb = m >> 11, tt = m & (N_CTX - 1);
          dst[((size_t)(bb * NH + h) * N_CTX + tt) * HD + d] = f2b((acc[mi][ni][r] + bv) * scl);
        }
      }
    }
  }
}

// ---------------- GEMM2: 128x64 tile, 3-buffer counted-vmcnt pipeline (fp32 out) ---------
__global__ __launch_bounds__(512, 4) void gemm_proj128(const u16* __restrict__ A,
                                                       const u16* __restrict__ Bt,
                                                       const float* __restrict__ bias,
                                                       float* __restrict__ out) {
  __shared__ __align__(16) u16 As[3][128 * 64];   // 48 KB
  __shared__ __align__(16) u16 Bs[3][64 * 64];    // 24 KB
  const int tid = threadIdx.x, w = tid >> 6, lane = tid & 63;
  const int g = lane >> 4, lr = lane & 15;
  const int wr = w >> 1, wc = w & 1;
  const int bid = blockIdx.x;
  const int swz = (bid & 7) * 64 + (bid >> 3);
  const int tm = (swz & 31) * 128, tn = (swz >> 5) * 64;

  f32x4 acc[2][2];
  #pragma unroll
  for (int mi = 0; mi < 2; ++mi)
    #pragma unroll
    for (int ni = 0; ni < 2; ++ni)
      acc[mi][ni] = (f32x4){0.f, 0.f, 0.f, 0.f};

  auto STAGE = [&](int d, int kt) {
    const int k0 = kt << 6;
    #pragma unroll
    for (int j = 0; j < 2; ++j) {
      int ci = j * 512 + tid, row = ci >> 3, c8 = ci & 7;
      GLDS16(A + (size_t)(tm + row) * CDIM + k0 + ((c8 ^ (row & 7)) << 3),
             &As[d][row * 64 + c8 * 8]);
    }
    {
      int row = tid >> 3, c8 = tid & 7;
      GLDS16(Bt + (size_t)(tn + row) * CDIM + k0 + ((c8 ^ (row & 7)) << 3),
             &Bs[d][row * 64 + c8 * 8]);
    }
  };

  STAGE(0, 0);
  STAGE(1, 1);
  asm volatile("s_waitcnt vmcnt(3)" ::: "memory");
  __builtin_amdgcn_s_barrier();

  const int x7 = lr & 7;
  int cur = 0;
  for (int t = 0; t < 16; ++t) {
    if (t < 14) STAGE((cur + 2) % 3, t + 2);

    frag_ab af[2][2], bf[2][2];
    #pragma unroll
    for (int mi = 0; mi < 2; ++mi) {
      int row = wr * 32 + mi * 16 + lr;
      #pragma unroll
      for (int ks = 0; ks < 2; ++ks)
        af[mi][ks] = *(const frag_ab*)&As[cur][row * 64 + ((((ks << 2) | g) ^ x7) << 3)];
    }
    #pragma unroll
    for (int ni = 0; ni < 2; ++ni) {
      int row = wc * 32 + ni * 16 + lr;
      #pragma unroll
      for (int ks = 0; ks < 2; ++ks)
        bf[ni][ks] = *(const frag_ab*)&Bs[cur][row * 64 + ((((ks << 2) | g) ^ x7) << 3)];
    }
    __builtin_amdgcn_s_setprio(1);
    #pragma unroll
    for (int mi = 0; mi < 2; ++mi)
      #pragma unroll
      for (int ni = 0; ni < 2; ++ni)
        #pragma unroll
        for (int ks = 0; ks < 2; ++ks)
          acc[mi][ni] = mfma16(af[mi][ks], bf[ni][ks], acc[mi][ni]);
    __builtin_amdgcn_s_setprio(0);

    if (t < 14) { asm volatile("s_waitcnt vmcnt(3)" ::: "memory"); }
    else        { asm volatile("s_waitcnt vmcnt(0)" ::: "memory"); }
    __builtin_amdgcn_s_barrier();
    cur = (cur + 1) % 3;
  }

  #pragma unroll
  for (int ni = 0; ni < 2; ++ni) {
    int n = tn + wc * 32 + ni * 16 + lr;
    float bv = bias[n];
    #pragma unroll
    for (int mi = 0; mi < 2; ++mi)
      #pragma unroll
      for (int r = 0; r < 4; ++r) {
        int m = tm + wr * 32 + mi * 16 + g * 4 + r;
        out[(size_t)m * CDIM + n] = acc[mi][ni][r] + bv;
      }
  }
}

// ---------------- flash attention (causal): one q-tile/block, split-K parity waves -------
// (R12 known-good version.) No-max exp2 softmax => k-split exact. Block = (bh, qt);
// 8 waves = 4 row-slices x 2 k-parities; single accumulator set per wave.
__global__ __launch_bounds__(512, 4) void attn_fwd(const u16* __restrict__ Q, const u16* __restrict__ K,
                                                   const u16* __restrict__ Vt, u16* __restrict__ Y) {
  __shared__ __align__(16) u16 Ks[4][64 * 64];    // 32 KB (reused as f32 scratch in epilogue)
  __shared__ __align__(16) u16 Vs[4][64 * 64];    // 32 KB
  const int orig = blockIdx.x;                    // 1024 blocks
  const int bh = (orig & 7) * 4 + ((orig >> 3) & 3);   // 4 bh per XCD
  const int qt = 31 - (orig >> 5);                     // heavy blocks dispatch first
  const int tid = threadIdx.x, w = tid >> 6, lane = tid & 63;
  const int grp = w >> 2, wq = w & 3;             // grp = k-parity, wq = 16-row slice
  const int g = lane >> 4, lr = lane & 15;
  const size_t base = (size_t)bh * N_CTX * HD;
  const u16* Kbh = K + base;
  const u16* Vbh = Vt + base;

  const int c8 = tid & 7, srow = (tid >> 3) & 63;
  const size_t kOff = (size_t)srow * HD + (size_t)((c8 ^ (srow & 7)) * 8);
  const size_t vOff = (size_t)srow * N_CTX + (size_t)((c8 ^ (srow & 7)) * 8);

  frag_ab qf[2];
  {
    const u16* qp = Q + base + (size_t)(qt * 64 + wq * 16 + lr) * HD + g * 8;
    qf[0] = *(const frag_ab*)qp;  qf[1] = *(const frag_ab*)(qp + 32);
  }

  float ps = 0.f;
  f32x4 o[4];
  #pragma unroll
  for (int d = 0; d < 4; ++d) o[d] = (f32x4){0.f, 0.f, 0.f, 0.f};

  auto STAGE = [&](int b, int kt) {
    GLDS16(Kbh + (size_t)kt * 64 * HD + kOff, &Ks[b][(size_t)tid * 8]);
    GLDS16(Vbh + (size_t)kt * 64 + vOff,      &Vs[b][(size_t)tid * 8]);
  };

  const int niter = (qt + 2) >> 1;
  STAGE(0, 0);
  STAGE(1, 1);
  asm volatile("s_waitcnt vmcnt(0)" ::: "memory");
  __builtin_amdgcn_s_barrier();

  const int qrow = wq * 16 + lr;
  for (int i = 0; i < niter; ++i) {
    const int t0 = 2 * i;
    const int t  = t0 + grp;                      // this wave's k-tile
    if (i + 1 < niter) { STAGE((t0 + 2) & 3, t0 + 2); STAGE((t0 + 3) & 3, t0 + 3); }

    if (t <= qt) {
      const int bb = t & 3;
      frag_ab kf[4][2];
      #pragma unroll
      for (int nf = 0; nf < 4; ++nf)
        #pragma unroll
        for (int ks = 0; ks < 2; ++ks)
          kf[nf][ks] = *(const frag_ab*)&Ks[bb][(size_t)(nf * 16 + lr) * 64 +
                                                (size_t)((((ks << 2) | g) ^ (lr & 7)) * 8)];
      f32x4 s[4];
      __builtin_amdgcn_s_setprio(1);
      #pragma unroll
      for (int j = 0; j < 4; ++j) {
        f32x4 a = (f32x4){0.f, 0.f, 0.f, 0.f};
        a = mfma16(kf[j][0], qf[0], a);
        a = mfma16(kf[j][1], qf[1], a);
        s[j] = a;
      }
      __builtin_amdgcn_s_setprio(0);
      if (t == qt) {                              // diagonal mask
        #pragma unroll
        for (int nf = 0; nf < 4; ++nf)
          #pragma unroll
          for (int r = 0; r < 4; ++r)
            if (nf * 16 + g * 4 + r > qrow) s[nf][r] = -1e30f;
      }
      #pragma unroll
      for (int j = 0; j < 4; ++j)
        #pragma unroll
        for (int r = 0; r < 4; ++r)
          s[j][r] = __builtin_amdgcn_exp2f(s[j][r]);
      ps += ((s[0][0]+s[0][1])+(s[0][2]+s[0][3])) + ((s[1][0]+s[1][1])+(s[1][2]+s[1][3]))
          + ((s[2][0]+s[2][1])+(s[2][2]+s[2][3])) + ((s[3][0]+s[3][1])+(s[3][2]+s[3][3]));
      frag_ab pa[2];
      #pragma unroll
      for (int ks = 0; ks < 2; ++ks)
        #pragma unroll
        for (int j = 0; j < 4; ++j) {
          pa[ks][j]     = (short)f2b(s[2 * ks][j]);
          pa[ks][4 + j] = (short)f2b(s[2 * ks + 1][j]);
        }
      #pragma unroll
      for (int d = 0; d < 4; ++d) {
        const int row = (d * 16 + lr) * 64;
        frag_ab vf[2];
        #pragma unroll
        for (int ks = 0; ks < 2; ++ks) {
          u16x4 lo = *(const u16x4*)&Vs[bb][row + (((ks * 4 + (g >> 1)) ^ (lr & 7)) * 8) + (g & 1) * 4];
          u16x4 hi = *(const u16x4*)&Vs[bb][row + (((ks * 4 + 2 + (g >> 1)) ^ (lr & 7)) * 8) + (g & 1) * 4];
          #pragma unroll
          for (int j = 0; j < 4; ++j) { vf[ks][j] = (short)lo[j]; vf[ks][4 + j] = (short)hi[j]; }
        }
        __builtin_amdgcn_s_setprio(1);
        o[d] = mfma16(pa[0], vf[0], o[d]);
        o[d] = mfma16(pa[1], vf[1], o[d]);
        __builtin_amdgcn_s_setprio(0);
      }
    }

    asm volatile("s_waitcnt vmcnt(0)" ::: "memory");
    __builtin_amdgcn_s_barrier();
  }

  // ---- epilogue: cross-parity combine via LDS, then O/ls -> Y ----
  ps += __shfl_xor(ps, 16, 64);
  ps += __shfl_xor(ps, 32, 64);

  float* SO = (float*)&Ks[0][0];        // 16 KB: grp1 partial O (64 rows x 64 cols)
  float* PS = (float*)&Vs[0][0];        // 64 floats: grp1 partial ps

  if (grp == 1) {
    #pragma unroll
    for (int d = 0; d < 4; ++d)
      #pragma unroll
      for (int r = 0; r < 4; ++r)
        SO[(wq * 16 + g * 4 + r) * 64 + d * 16 + lr] = o[d][r];
    if (g == 0) PS[wq * 16 + lr] = ps;
  }
  __syncthreads();

  if (grp == 0) {
    const int b = bh >> 4, h = bh & 15;
    float li = 1.0f / (ps + PS[wq * 16 + lr]);
    #pragma unroll
    for (int r = 0; r < 4; ++r) {
      int src = (lane & 48) | (((lane >> 4) & 3) * 4 + r);
      float lir = __shfl(li, src, 64);
      int row = qt * 64 + wq * 16 + g * 4 + r;
      #pragma unroll
      for (int d = 0; d < 4; ++d) {
        float val = (o[d][r] + SO[(wq * 16 + g * 4 + r) * 64 + d * 16 + lr]) * lir;
        Y[((size_t)(b * N_CTX + row)) * CDIM + h * HD + d * 16 + lr] = f2b(val);
      }
    }
  }
}

// ---------------- launch ----------------
extern "C" void kernel_launch(void* const* d_in, const int* in_sizes, int n_in,
                              void* d_out, int out_size, void* d_ws, size_t ws_size,
                              hipStream_t stream) {
  const float* x      = (const float*)d_in[0];
  const float* W_attn = (const float*)d_in[1];
  const float* b_attn = (const float*)d_in[2];
  const float* W_proj = (const float*)d_in[3];
  const float* b_proj = (const float*)d_in[4];
  float* out = (float*)d_out;
  char* ws = (char*)d_ws;

  u16* xb  = (u16*)(ws);                       // 8 MB  (reused for y)
  u16* Wab = (u16*)(ws + ((size_t)8 << 20));   // 6 MB  W_attn^T bf16
  u16* Wpb = (u16*)(ws + ((size_t)14 << 20));  // 2 MB  W_proj^T bf16
  u16* Qb  = (u16*)(ws + ((size_t)16 << 20));  // 8 MB  (pre-scaled)
  u16* Kb  = (u16*)(ws + ((size_t)24 << 20));  // 8 MB
  u16* Vtb = (u16*)(ws + ((size_t)32 << 20));  // 8 MB  V^T
  u16* yb  = xb;

  prep_all<<<6144, 256, 0, stream>>>(x, xb, W_attn, Wab, W_proj, Wpb);
  gemm_qkv128<<<512, 256, 0, stream>>>(xb, Wab, b_attn, Qb, Kb, Vtb);
  attn_fwd<<<1024, 512, 0, stream>>>(Qb, Kb, Vtb, yb);
  gemm_proj128<<<512, 512, 0, stream>>>(yb, Wpb, b_proj, out);
}

// Round 17
// 89.437 us; speedup vs baseline: 1.0613x; 1.0107x over previous
//
#include <hip/hip_runtime.h>
#include <hip/hip_bf16.h>

typedef unsigned short u16;
using frag_ab = __attribute__((ext_vector_type(8))) short;
using f32x4   = __attribute__((ext_vector_type(4))) float;
using u16x4   = __attribute__((ext_vector_type(4))) unsigned short;
using u16x8   = __attribute__((ext_vector_type(8))) unsigned short;

#define N_CTX   2048
#define NBATCH  2
#define CDIM    1024
#define NH      16
#define HD      64

__device__ __forceinline__ u16 f2b(float f) {
  __hip_bfloat16 h = __float2bfloat16(f);
  return __builtin_bit_cast(u16, h);
}

__device__ __forceinline__ f32x4 mfma16(frag_ab a, frag_ab b, f32x4 c) {
  return __builtin_amdgcn_mfma_f32_16x16x32_bf16(a, b, c, 0, 0, 0);
}

#define GLDS16(src, dst) \
  __builtin_amdgcn_global_load_lds((const __attribute__((address_space(1))) void*)(src), \
                                   (__attribute__((address_space(3))) void*)(dst), 16, 0, 0)

// ---------------- merged prep kernel ----------------
__global__ __launch_bounds__(256) void prep_all(const float* __restrict__ x, u16* __restrict__ xb,
                                                const float* __restrict__ Wa, u16* __restrict__ Wab,
                                                const float* __restrict__ Wp, u16* __restrict__ Wpb) {
  __shared__ float tile[32][33];
  const int blk = blockIdx.x;
  if (blk < 2048) {
    int i = blk * 256 + threadIdx.x;
    const f32x4* ip = (const f32x4*)x;
    f32x4 a = ip[2 * i], b2 = ip[2 * i + 1];
    u16x8 r;
    #pragma unroll
    for (int j = 0; j < 4; ++j) { r[j] = f2b(a[j]); r[4 + j] = f2b(b2[j]); }
    ((u16x8*)xb)[i] = r;
    return;
  }
  const float* in; u16* out; int K, N, bx, by;
  if (blk < 5120) {
    int idx = blk - 2048; in = Wa; out = Wab; K = CDIM; N = 3 * CDIM;
    bx = idx % 96; by = idx / 96;
  } else {
    int idx = blk - 5120; in = Wp; out = Wpb; K = CDIM; N = CDIM;
    bx = idx & 31; by = idx >> 5;
  }
  int n0 = bx * 32, k0 = by * 32;
  int c = threadIdx.x & 31, r0 = threadIdx.x >> 5;
  #pragma unroll
  for (int i = 0; i < 4; ++i) {
    int r = r0 + i * 8;
    tile[r][c] = in[(size_t)(k0 + r) * N + n0 + c];
  }
  __syncthreads();
  // vectorized transpose write: thread (n, kq) packs 4 contiguous k into one u16x4
  int n = threadIdx.x >> 3, kq = threadIdx.x & 7;
  u16x4 pk;
  #pragma unroll
  for (int j = 0; j < 4; ++j) pk[j] = f2b(tile[kq * 4 + j][n]);
  *(u16x4*)&out[(size_t)(n0 + n) * K + k0 + kq * 4] = pk;
}

// ---------------- GEMM1: 128x192 tile, 8 waves, 2 blocks/CU ----------------
__global__ __launch_bounds__(512, 4) void gemm_qkv128(const u16* __restrict__ A,
                                                      const u16* __restrict__ Bt,
                                                      const float* __restrict__ bias,
                                                      u16* __restrict__ Qo, u16* __restrict__ Ko,
                                                      u16* __restrict__ Vto) {
  __shared__ __align__(16) u16 As[2][128 * 64];   // 32 KB
  __shared__ __align__(16) u16 Bs[2][192 * 64];   // 48 KB
  const int tid = threadIdx.x, w = tid >> 6, lane = tid & 63;
  const int g = lane >> 4, lr = lane & 15;
  const int wr = w >> 2, wc = w & 3;
  const int bid = blockIdx.x;
  const int swz = (bid & 7) * 64 + (bid >> 3);
  const int tm = (swz & 31) * 128, tn = (swz >> 5) * 192;

  f32x4 acc[4][3];
  #pragma unroll
  for (int mi = 0; mi < 4; ++mi)
    #pragma unroll
    for (int ni = 0; ni < 3; ++ni)
      acc[mi][ni] = (f32x4){0.f, 0.f, 0.f, 0.f};

  auto STAGE = [&](int d, int kt) {
    const int k0 = kt << 6;
    #pragma unroll
    for (int j = 0; j < 2; ++j) {
      int ci = j * 512 + tid, row = ci >> 3, c8 = ci & 7;
      GLDS16(A + (size_t)(tm + row) * CDIM + k0 + ((c8 ^ (row & 7)) << 3),
             &As[d][row * 64 + c8 * 8]);
    }
    #pragma unroll
    for (int j = 0; j < 3; ++j) {
      int ci = j * 512 + tid, row = ci >> 3, c8 = ci & 7;
      GLDS16(Bt + (size_t)(tn + row) * CDIM + k0 + ((c8 ^ (row & 7)) << 3),
             &Bs[d][row * 64 + c8 * 8]);
    }
  };

  STAGE(0, 0);
  asm volatile("s_waitcnt vmcnt(0)" ::: "memory");
  __builtin_amdgcn_s_barrier();

  const int x7 = lr & 7;
  for (int t = 0; t < 16; ++t) {
    const int cur = t & 1;
    if (t < 15) STAGE(cur ^ 1, t + 1);

    frag_ab af[4][2], bf[3][2];
    #pragma unroll
    for (int mi = 0; mi < 4; ++mi) {
      int row = wr * 64 + mi * 16 + lr;
      #pragma unroll
      for (int ks = 0; ks < 2; ++ks)
        af[mi][ks] = *(const frag_ab*)&As[cur][row * 64 + ((((ks << 2) | g) ^ x7) << 3)];
    }
    #pragma unroll
    for (int ni = 0; ni < 3; ++ni) {
      int row = wc * 48 + ni * 16 + lr;
      #pragma unroll
      for (int ks = 0; ks < 2; ++ks)
        bf[ni][ks] = *(const frag_ab*)&Bs[cur][row * 64 + ((((ks << 2) | g) ^ x7) << 3)];
    }
    __builtin_amdgcn_s_setprio(1);
    #pragma unroll
    for (int mi = 0; mi < 4; ++mi)
      #pragma unroll
      for (int ni = 0; ni < 3; ++ni)
        #pragma unroll
        for (int ks = 0; ks < 2; ++ks)
          acc[mi][ni] = mfma16(af[mi][ks], bf[ni][ks], acc[mi][ni]);
    __builtin_amdgcn_s_setprio(0);

    asm volatile("s_waitcnt vmcnt(0)" ::: "memory");
    __builtin_amdgcn_s_barrier();
  }

  #pragma unroll
  for (int ni = 0; ni < 3; ++ni) {
    int n = tn + wc * 48 + ni * 16 + lr;
    float bv = bias[n];
    int which = n >> 10, c = n & 1023, h = c >> 6, d = c & 63;
    #pragma unroll
    for (int mi = 0; mi < 4; ++mi) {
      if (which == 2) {
        int t0 = tm + wr * 64 + mi * 16 + g * 4;
        int bb = t0 >> 11, tt = t0 & (N_CTX - 1);
        u16x4 pk;
        #pragma unroll
        for (int r = 0; r < 4; ++r) pk[r] = f2b(acc[mi][ni][r] + bv);
        *(u16x4*)&Vto[((size_t)(bb * NH + h) * HD + d) * N_CTX + tt] = pk;
      } else {
        u16* dst = (which == 0) ? Qo : Ko;
        float scl = (which == 0) ? 0.180336881f : 1.0f;   // (1/8)*log2(e)
        #pragma unroll
        for (int r = 0; r < 4; ++r) {
          int m = tm + wr * 64 + mi * 16 + g * 4 + r;
          int bb = m >> 11, tt = m & (N_CTX - 1);
          dst[((size_t)(bb * NH + h) * N_CTX + tt) * HD + d] = f2b((acc[mi][ni][r] + bv) * scl);
        }
      }
    }
  }
}

// ---------------- GEMM2: 128x64 tile, 3-buffer counted-vmcnt pipeline (fp32 out) ---------
__global__ __launch_bounds__(512, 4) void gemm_proj128(const u16* __restrict__ A,
                                                       const u16* __restrict__ Bt,
                                                       const float* __restrict__ bias,
                                                       float* __restrict__ out) {
  __shared__ __align__(16) u16 As[3][128 * 64];   // 48 KB
  __shared__ __align__(16) u16 Bs[3][64 * 64];    // 24 KB
  const int tid = threadIdx.x, w = tid >> 6, lane = tid & 63;
  const int g = lane >> 4, lr = lane & 15;
  const int wr = w >> 1, wc = w & 1;
  const int bid = blockIdx.x;
  const int swz = (bid & 7) * 64 + (bid >> 3);
  const int tm = (swz & 31) * 128, tn = (swz >> 5) * 64;

  f32x4 acc[2][2];
  #pragma unroll
  for (int mi = 0; mi < 2; ++mi)
    #pragma unroll
    for (int ni = 0; ni < 2; ++ni)
      acc[mi][ni] = (f32x4){0.f, 0.f, 0.f, 0.f};

  auto STAGE = [&](int d, int kt) {               // 3 loads per call
    const int k0 = kt << 6;
    #pragma unroll
    for (int j = 0; j < 2; ++j) {
      int ci = j * 512 + tid, row = ci >> 3, c8 = ci & 7;
      GLDS16(A + (size_t)(tm + row) * CDIM + k0 + ((c8 ^ (row & 7)) << 3),
             &As[d][row * 64 + c8 * 8]);
    }
    {
      int row = tid >> 3, c8 = tid & 7;
      GLDS16(Bt + (size_t)(tn + row) * CDIM + k0 + ((c8 ^ (row & 7)) << 3),
             &Bs[d][row * 64 + c8 * 8]);
    }
  };

  STAGE(0, 0);
  STAGE(1, 1);
  asm volatile("s_waitcnt vmcnt(3)" ::: "memory");   // tile 0 landed; tile 1 in flight
  __builtin_amdgcn_s_barrier();

  const int x7 = lr & 7;
  int cur = 0;
  for (int t = 0; t < 16; ++t) {
    if (t < 14) STAGE((cur + 2) % 3, t + 2);

    frag_ab af[2][2], bf[2][2];
    #pragma unroll
    for (int mi = 0; mi < 2; ++mi) {
      int row = wr * 32 + mi * 16 + lr;
      #pragma unroll
      for (int ks = 0; ks < 2; ++ks)
        af[mi][ks] = *(const frag_ab*)&As[cur][row * 64 + ((((ks << 2) | g) ^ x7) << 3)];
    }
    #pragma unroll
    for (int ni = 0; ni < 2; ++ni) {
      int row = wc * 32 + ni * 16 + lr;
      #pragma unroll
      for (int ks = 0; ks < 2; ++ks)
        bf[ni][ks] = *(const frag_ab*)&Bs[cur][row * 64 + ((((ks << 2) | g) ^ x7) << 3)];
    }
    __builtin_amdgcn_s_setprio(1);
    #pragma unroll
    for (int mi = 0; mi < 2; ++mi)
      #pragma unroll
      for (int ni = 0; ni < 2; ++ni)
        #pragma unroll
        for (int ks = 0; ks < 2; ++ks)
          acc[mi][ni] = mfma16(af[mi][ks], bf[ni][ks], acc[mi][ni]);
    __builtin_amdgcn_s_setprio(0);

    if (t < 14) { asm volatile("s_waitcnt vmcnt(3)" ::: "memory"); }
    else        { asm volatile("s_waitcnt vmcnt(0)" ::: "memory"); }
    __builtin_amdgcn_s_barrier();
    cur = (cur + 1) % 3;
  }

  #pragma unroll
  for (int ni = 0; ni < 2; ++ni) {
    int n = tn + wc * 32 + ni * 16 + lr;
    float bv = bias[n];
    #pragma unroll
    for (int mi = 0; mi < 2; ++mi)
      #pragma unroll
      for (int r = 0; r < 4; ++r) {
        int m = tm + wr * 32 + mi * 16 + g * 4 + r;
        out[(size_t)m * CDIM + n] = acc[mi][ni][r] + bv;
      }
  }
}

// ---------------- flash attention (causal): one q-tile/block, split-K parity waves -------
// (R12 known-good.) No-max exp2 softmax => O/ls pure sums => k-split exact. Block=(bh,qt);
// 8 waves = 4 row-slices x 2 k-parities; single accumulator set per wave.
__global__ __launch_bounds__(512, 4) void attn_fwd(const u16* __restrict__ Q, const u16* __restrict__ K,
                                                   const u16* __restrict__ Vt, u16* __restrict__ Y) {
  __shared__ __align__(16) u16 Ks[4][64 * 64];    // 32 KB (f32 scratch in epilogue)
  __shared__ __align__(16) u16 Vs[4][64 * 64];    // 32 KB
  const int orig = blockIdx.x;                    // 1024 blocks
  const int bh = (orig & 7) * 4 + ((orig >> 3) & 3);   // 4 bh per XCD
  const int qt = 31 - (orig >> 5);                     // heavy blocks dispatch first
  const int tid = threadIdx.x, w = tid >> 6, lane = tid & 63;
  const int grp = w >> 2, wq = w & 3;             // grp = k-parity, wq = 16-row slice
  const int g = lane >> 4, lr = lane & 15;
  const size_t base = (size_t)bh * N_CTX * HD;
  const u16* Kbh = K + base;
  const u16* Vbh = Vt + base;

  const int c8 = tid & 7, srow = (tid >> 3) & 63;
  const size_t kOff = (size_t)srow * HD + (size_t)((c8 ^ (srow & 7)) * 8);
  const size_t vOff = (size_t)srow * N_CTX + (size_t)((c8 ^ (srow & 7)) * 8);

  frag_ab qf[2];
  {
    const u16* qp = Q + base + (size_t)(qt * 64 + wq * 16 + lr) * HD + g * 8;
    qf[0] = *(const frag_ab*)qp;  qf[1] = *(const frag_ab*)(qp + 32);
  }

  float ps = 0.f;
  f32x4 o[4];
  #pragma unroll
  for (int d = 0; d < 4; ++d) o[d] = (f32x4){0.f, 0.f, 0.f, 0.f};

  auto STAGE = [&](int b, int kt) {
    GLDS16(Kbh + (size_t)kt * 64 * HD + kOff, &Ks[b][(size_t)tid * 8]);
    GLDS16(Vbh + (size_t)kt * 64 + vOff,      &Vs[b][(size_t)tid * 8]);
  };

  const int niter = (qt + 2) >> 1;
  STAGE(0, 0);
  STAGE(1, 1);
  asm volatile("s_waitcnt vmcnt(0)" ::: "memory");
  __builtin_amdgcn_s_barrier();

  const int qrow = wq * 16 + lr;
  for (int i = 0; i < niter; ++i) {
    const int t0 = 2 * i;
    const int t  = t0 + grp;                      // this wave's k-tile
    if (i + 1 < niter) { STAGE((t0 + 2) & 3, t0 + 2); STAGE((t0 + 3) & 3, t0 + 3); }

    if (t <= qt) {
      const int bb = t & 3;
      frag_ab kf[4][2];
      #pragma unroll
      for (int nf = 0; nf < 4; ++nf)
        #pragma unroll
        for (int ks = 0; ks < 2; ++ks)
          kf[nf][ks] = *(const frag_ab*)&Ks[bb][(size_t)(nf * 16 + lr) * 64 +
                                                (size_t)((((ks << 2) | g) ^ (lr & 7)) * 8)];
      f32x4 s[4];
      __builtin_amdgcn_s_setprio(1);
      #pragma unroll
      for (int j = 0; j < 4; ++j) {
        f32x4 a = (f32x4){0.f, 0.f, 0.f, 0.f};
        a = mfma16(kf[j][0], qf[0], a);
        a = mfma16(kf[j][1], qf[1], a);
        s[j] = a;
      }
      __builtin_amdgcn_s_setprio(0);
      if (t == qt) {                              // diagonal mask
        #pragma unroll
        for (int nf = 0; nf < 4; ++nf)
          #pragma unroll
          for (int r = 0; r < 4; ++r)
            if (nf * 16 + g * 4 + r > qrow) s[nf][r] = -1e30f;
      }
      #pragma unroll
      for (int j = 0; j < 4; ++j)
        #pragma unroll
        for (int r = 0; r < 4; ++r)
          s[j][r] = __builtin_amdgcn_exp2f(s[j][r]);
      ps += ((s[0][0]+s[0][1])+(s[0][2]+s[0][3])) + ((s[1][0]+s[1][1])+(s[1][2]+s[1][3]))
          + ((s[2][0]+s[2][1])+(s[2][2]+s[2][3])) + ((s[3][0]+s[3][1])+(s[3][2]+s[3][3]));
      frag_ab pa[2];
      #pragma unroll
      for (int ks = 0; ks < 2; ++ks)
        #pragma unroll
        for (int j = 0; j < 4; ++j) {
          pa[ks][j]     = (short)f2b(s[2 * ks][j]);
          pa[ks][4 + j] = (short)f2b(s[2 * ks + 1][j]);
        }
      #pragma unroll
      for (int d = 0; d < 4; ++d) {
        const int row = (d * 16 + lr) * 64;
        frag_ab vf[2];
        #pragma unroll
        for (int ks = 0; ks < 2; ++ks) {
          u16x4 lo = *(const u16x4*)&Vs[bb][row + (((ks * 4 + (g >> 1)) ^ (lr & 7)) * 8) + (g & 1) * 4];
          u16x4 hi = *(const u16x4*)&Vs[bb][row + (((ks * 4 + 2 + (g >> 1)) ^ (lr & 7)) * 8) + (g & 1) * 4];
          #pragma unroll
          for (int j = 0; j < 4; ++j) { vf[ks][j] = (short)lo[j]; vf[ks][4 + j] = (short)hi[j]; }
        }
        __builtin_amdgcn_s_setprio(1);
        o[d] = mfma16(pa[0], vf[0], o[d]);
        o[d] = mfma16(pa[1], vf[1], o[d]);
        __builtin_amdgcn_s_setprio(0);
      }
    }

    asm volatile("s_waitcnt vmcnt(0)" ::: "memory");
    __builtin_amdgcn_s_barrier();
  }

  // ---- epilogue: cross-parity combine via LDS, then O/ls -> Y ----
  ps += __shfl_xor(ps, 16, 64);
  ps += __shfl_xor(ps, 32, 64);

  float* SO = (float*)&Ks[0][0];        // 16 KB: grp1 partial O (64 rows x 64 cols)
  float* PS = (float*)&Vs[0][0];        // 64 floats: grp1 partial ps

  if (grp == 1) {
    #pragma unroll
    for (int d = 0; d < 4; ++d)
      #pragma unroll
      for (int r = 0; r < 4; ++r)
        SO[(wq * 16 + g * 4 + r) * 64 + d * 16 + lr] = o[d][r];
    if (g == 0) PS[wq * 16 + lr] = ps;
  }
  __syncthreads();

  if (grp == 0) {
    const int b = bh >> 4, h = bh & 15;
    float li = 1.0f / (ps + PS[wq * 16 + lr]);
    #pragma unroll
    for (int r = 0; r < 4; ++r) {
      int src = (lane & 48) | (((lane >> 4) & 3) * 4 + r);
      float lir = __shfl(li, src, 64);
      int row = qt * 64 + wq * 16 + g * 4 + r;
      #pragma unroll
      for (int d = 0; d < 4; ++d) {
        float val = (o[d][r] + SO[(wq * 16 + g * 4 + r) * 64 + d * 16 + lr]) * lir;
        Y[((size_t)(b * N_CTX + row)) * CDIM + h * HD + d * 16 + lr] = f2b(val);
      }
    }
  }
}

// ---------------- launch ----------------
extern "C" void kernel_launch(void* const* d_in, const int* in_sizes, int n_in,
                              void* d_out, int out_size, void* d_ws, size_t ws_size,
                              hipStream_t stream) {
  const float* x      = (const float*)d_in[0];
  const float* W_attn = (const float*)d_in[1];
  const float* b_attn = (const float*)d_in[2];
  const float* W_proj = (const float*)d_in[3];
  const float* b_proj = (const float*)d_in[4];
  float* out = (float*)d_out;
  char* ws = (char*)d_ws;

  u16* xb  = (u16*)(ws);                       // 8 MB  (reused for y)
  u16* Wab = (u16*)(ws + ((size_t)8 << 20));   // 6 MB  W_attn^T bf16
  u16* Wpb = (u16*)(ws + ((size_t)14 << 20));  // 2 MB  W_proj^T bf16
  u16* Qb  = (u16*)(ws + ((size_t)16 << 20));  // 8 MB  (pre-scaled)
  u16* Kb  = (u16*)(ws + ((size_t)24 << 20));  // 8 MB
  u16* Vtb = (u16*)(ws + ((size_t)32 << 20));  // 8 MB  V^T
  u16* yb  = xb;

  prep_all<<<6144, 256, 0, stream>>>(x, xb, W_attn, Wab, W_proj, Wpb);
  gemm_qkv128<<<512, 512, 0, stream>>>(xb, Wab, b_attn, Qb, Kb, Vtb);
  attn_fwd<<<1024, 512, 0, stream>>>(Qb, Kb, Vtb, yb);
  gemm_proj128<<<512, 512, 0, stream>>>(yb, Wpb, b_proj, out);
}